// Round 12
// baseline (166.629 us; speedup 1.0000x reference)
//
#include <hip/hip_runtime.h>
#include <hip/hip_bf16.h>

// Sizes (fixed by the reference)
#define BDIM 2
#define TDIM 1024
#define DDIM 1024
#define HDIM 16
#define HD   64
#define RROWS (BDIM * TDIM)        // 2048 rows for the big GEMMs
#define BH    (BDIM * HDIM)        // 32 (b,h) pairs
#define NHE   (BH * TDIM * HD)     // 2,097,152 elements in head layout
#define NHE4  (NHE / 4)
#define DIFF_BLOCKS 512            // = attn grid (16 qb x 32 bh)
#define L2E 1.4426950408889634f

typedef __attribute__((ext_vector_type(8))) short short8v;
typedef __attribute__((ext_vector_type(4))) short short4v;
typedef __attribute__((ext_vector_type(8))) _Float16 half8v;
typedef __attribute__((ext_vector_type(4))) _Float16 half4v;
typedef __attribute__((ext_vector_type(4))) float f32x4;

struct FState {
  int   cw;
  float temp;
  int   done;
  int   upd;
  int   done_prev;
  float thr;
  float fac;
  int   pad;
};

static __device__ __forceinline__ unsigned short f2bf(float x) {
  __hip_bfloat16 h = __float2bfloat16(x);
  return __builtin_bit_cast(unsigned short, h);
}
// async global->LDS, 16B per lane. LDS dest is wave-uniform base (+lane*16 by HW).
static __device__ __forceinline__ void gload16(const void* g, void* l) {
  __builtin_amdgcn_global_load_lds(
      (const __attribute__((address_space(1))) void*)g,
      (__attribute__((address_space(3))) void*)l, 16, 0, 0);
}

// ---------------------------------------------------------------------------
// prep: one launch = init state/counters + LN(x) (fp16) + weight f32->fp16.
// 1-D grid, range-decoded: [0,2048) ln rows; [2048,6144) big-W rows;
// [6144,6148) lqw rows; 6148 init.
// ---------------------------------------------------------------------------
__global__ __launch_bounds__(256) void prep_kernel(
    const float* __restrict__ x, const float* __restrict__ wa, const float* __restrict__ wb,
    _Float16* __restrict__ xaH, _Float16* __restrict__ xbH,
    const float* __restrict__ W0, const float* __restrict__ W1,
    const float* __restrict__ W2, const float* __restrict__ W3,
    const float* __restrict__ W4,
    _Float16* __restrict__ O0, _Float16* __restrict__ O1,
    _Float16* __restrict__ O2, _Float16* __restrict__ O3,
    _Float16* __restrict__ O4,
    FState* st, float* accF, unsigned* cnt,
    const float* thr, const float* tb, const float* fac)
{
  const int bid = blockIdx.x;
  const int tid = threadIdx.x;

  if (bid >= 6148) {                       // ---- init ----
    if (tid == 0) {
      st->cw = TDIM;
      st->temp = tb[0];
      st->done = 0;
      st->done_prev = 0;
      st->upd = 1;
      st->thr = thr[0];
      st->fac = fac[0];
      accF[0] = 0.f; accF[1] = 0.f; accF[2] = 0.f;
      cnt[0] = 0u; cnt[1] = 0u; cnt[2] = 0u;
    }
    return;
  }

  if (bid >= 2048) {                       // ---- weight convert ----
    const int idx = bid - 2048;
    const float* W; _Float16* O; int r;
    if (bid >= 6144) { W = W4; O = O4; r = bid - 6144; }
    else {
      const int mat = idx >> 10;
      r = idx & 1023;
      switch (mat) {
        case 0:  W = W0; O = O0; break;
        case 1:  W = W1; O = O1; break;
        case 2:  W = W2; O = O2; break;
        default: W = W3; O = O3; break;
      }
    }
    const float4 v = reinterpret_cast<const float4*>(W + (size_t)r * 1024)[tid];
    half4v h;
    h[0] = (_Float16)v.x; h[1] = (_Float16)v.y;
    h[2] = (_Float16)v.z; h[3] = (_Float16)v.w;
    *reinterpret_cast<half4v*>(O + (size_t)r * 1024 + tid * 4) = h;
    return;
  }

  // ---- LayerNorm of x (shared mean/var, two weights) ----
  const int row = bid;
  const float4 v = reinterpret_cast<const float4*>(x + (size_t)row * DDIM)[tid];
  float s = v.x + v.y + v.z + v.w;
  float q = v.x * v.x + v.y * v.y + v.z * v.z + v.w * v.w;
#pragma unroll
  for (int off = 1; off < 64; off <<= 1) {
    s += __shfl_xor(s, off);
    q += __shfl_xor(q, off);
  }
  __shared__ float ss[4], qq[4];
  const int lane = tid & 63, wv = tid >> 6;
  if (lane == 0) { ss[wv] = s; qq[wv] = q; }
  __syncthreads();
  s = ss[0] + ss[1] + ss[2] + ss[3];
  q = qq[0] + qq[1] + qq[2] + qq[3];
  const float mean = s * (1.0f / DDIM);
  const float var  = q * (1.0f / DDIM) - mean * mean;
  const float inv  = rsqrtf(var + 1e-5f);
  const float4 a4 = reinterpret_cast<const float4*>(wa)[tid];
  const float4 b4 = reinterpret_cast<const float4*>(wb)[tid];
  const float hv[4] = { (v.x - mean) * inv, (v.y - mean) * inv,
                        (v.z - mean) * inv, (v.w - mean) * inv };
  const float av[4] = { a4.x, a4.y, a4.z, a4.w };
  const float bv[4] = { b4.x, b4.y, b4.z, b4.w };
  half4v ha, hb;
#pragma unroll
  for (int j = 0; j < 4; ++j) {
    ha[j] = (_Float16)(hv[j] * av[j]);
    hb[j] = (_Float16)(hv[j] * bv[j]);
  }
  *reinterpret_cast<half4v*>(xaH + (size_t)row * DDIM + tid * 4) = ha;
  *reinterpret_cast<half4v*>(xbH + (size_t)row * DDIM + tid * 4) = hb;
}

// ---------------------------------------------------------------------------
// fp16 MFMA GEMM: C = (A @ W^T + bias) * scale, fp32 accumulation.
// 128x64 tile (grid 16x16xZ = 3 blocks/CU), BK=32, 4 waves (2x2),
// 4x2 16x16x32 frags per wave. Staging via global_load_lds, linear LDS.
// CMODE 0: C row-major f32. CMODE 1: C scattered to head layout [B,H,T,64].
// ---------------------------------------------------------------------------
template<int CMODE>
__global__ __launch_bounds__(256) void gemm_mfma_kernel(
    const _Float16* __restrict__ A0, const _Float16* __restrict__ W0,
    const float* __restrict__ b0, float* __restrict__ C0, float s0,
    const _Float16* __restrict__ A1, const _Float16* __restrict__ W1,
    const float* __restrict__ b1, float* __restrict__ C1, float s1,
    const _Float16* __restrict__ A2, const _Float16* __restrict__ W2,
    const float* __restrict__ b2, float* __restrict__ C2, float s2)
{
  const _Float16* A; const _Float16* W; const float* bias; float* C; float scale;
  switch (blockIdx.z) {
    case 0:  A = A0; W = W0; bias = b0; C = C0; scale = s0; break;
    case 1:  A = A1; W = W1; bias = b1; C = C1; scale = s1; break;
    default: A = A2; W = W2; bias = b2; C = C2; scale = s2; break;
  }
  __shared__ __align__(16) _Float16 As[128 * 32];
  __shared__ __align__(16) _Float16 Ws[64 * 32];
  const int tid = threadIdx.x;
  const int wv = tid >> 6, lane = tid & 63;
  const int wm = wv >> 1, wn = wv & 1;
  const int bm = blockIdx.x;           // 16 M-blocks (2048/128)
  const int bn = blockIdx.y;           // 16 N-blocks (1024/64)

  // A staging: 2 instrs/wave (chunks wv*2+j of 16 rows); W: 1 instr/wave.
  const _Float16* gA[2];
  _Float16* lA[2];
#pragma unroll
  for (int j = 0; j < 2; ++j) {
    const int chunk = wv * 2 + j;                  // 0..7
    const int r = chunk * 16 + (lane >> 2);
    const int ce = (lane & 3) * 8;
    gA[j] = A + (size_t)(bm * 128 + r) * 1024 + ce;
    lA[j] = As + chunk * 512;
  }
  const _Float16* gW = W + (size_t)(bn * 64 + wv * 16 + (lane >> 2)) * 1024 + (lane & 3) * 8;
  _Float16* lW = Ws + wv * 512;

  f32x4 acc[4][2] = {};
  const int rb = lane & 15;
  const int kb = (lane >> 4) * 8;

  for (int ks = 0; ks < 1024; ks += 32) {
    __syncthreads();
#pragma unroll
    for (int j = 0; j < 2; ++j) gload16(gA[j] + ks, lA[j]);
    gload16(gW + ks, lW);
    __syncthreads();
    half8v af[4], wf[2];
#pragma unroll
    for (int f = 0; f < 4; ++f)
      af[f] = *reinterpret_cast<const half8v*>(As + (wm * 64 + f * 16 + rb) * 32 + kb);
#pragma unroll
    for (int f = 0; f < 2; ++f)
      wf[f] = *reinterpret_cast<const half8v*>(Ws + (wn * 32 + f * 16 + rb) * 32 + kb);
#pragma unroll
    for (int i = 0; i < 4; ++i)
#pragma unroll
      for (int j2 = 0; j2 < 2; ++j2)
        acc[i][j2] = __builtin_amdgcn_mfma_f32_16x16x32_f16(af[i], wf[j2], acc[i][j2], 0, 0, 0);
  }

#pragma unroll
  for (int j2 = 0; j2 < 2; ++j2) {
    const int n = bn * 64 + wn * 32 + j2 * 16 + (lane & 15);
    const float bv_ = bias ? bias[n] : 0.0f;
#pragma unroll
    for (int i = 0; i < 4; ++i) {
#pragma unroll
      for (int r = 0; r < 4; ++r) {
        const int m = bm * 128 + wm * 64 + i * 16 + (lane >> 4) * 4 + r;
        const float v = (acc[i][j2][r] + bv_) * scale;
        size_t ci;
        if constexpr (CMODE == 0) {
          ci = (size_t)m * 1024 + n;
        } else {
          const int b = m >> 10, t = m & (TDIM - 1);
          ci = ((size_t)(b * HDIM + (n >> 6)) * TDIM + t) * HD + (n & 63);
        }
        C[ci] = v;
      }
    }
  }
}

// ---------------------------------------------------------------------------
// per-head 64x64 projection body (iteration-invariant k/v paths)
// ---------------------------------------------------------------------------
template<int OUT_MODE, bool DO_LN>
static __device__ __forceinline__ void headproj_body(
    const float* __restrict__ in, unsigned short* __restrict__ out,
    const float* __restrict__ w, const float* __restrict__ bias,
    const float* __restrict__ lnw, float* wl, unsigned short* tT)
{
  const int tid = threadIdx.x;
  for (int idx = tid; idx < 4096; idx += 256) {
    const int d = idx >> 6, i = idx & 63;
    wl[i * 65 + d] = w[idx];
  }
  const int lane = tid & 63, wv = tid >> 6;
  const float bd = bias[lane];
  float lw = 1.0f;
  if constexpr (DO_LN) lw = lnw[lane];
  __syncthreads();
  const int rowBase = blockIdx.x * 32 + wv * 8;
  for (int rr = 0; rr < 8; ++rr) {
    const int row = rowBase + rr;
    const float h = in[(size_t)row * HD + lane];
    float y = bd;
#pragma unroll
    for (int i = 0; i < 64; ++i) {
      const float hv = __uint_as_float((unsigned)__builtin_amdgcn_readlane((int)__float_as_uint(h), i));
      y += wl[i * 65 + lane] * hv;
    }
    if constexpr (DO_LN) {
      float s = y;
#pragma unroll
      for (int off = 1; off < 64; off <<= 1) s += __shfl_xor(s, off);
      const float mean = s * (1.0f / 64.0f);
      const float t0 = y - mean;
      float v2 = t0 * t0;
#pragma unroll
      for (int off = 1; off < 64; off <<= 1) v2 += __shfl_xor(v2, off);
      y = t0 * rsqrtf(v2 * (1.0f / 64.0f) + 1e-5f) * lw;
    }
    if constexpr (OUT_MODE == 0) {
      out[(size_t)row * HD + lane] = f2bf(y);
    } else {
      tT[lane * 34 + wv * 8 + rr] = f2bf(y);
    }
  }
  if constexpr (OUT_MODE == 1) {
    __syncthreads();
    const int hd = tid >> 2, tseg = (tid & 3) * 8;
    const int r0 = blockIdx.x * 32;
    const int bh = r0 >> 10, t0 = r0 & (TDIM - 1);
    short8v v;
#pragma unroll
    for (int i = 0; i < 8; ++i) v[i] = (short)tT[hd * 34 + tseg + i];
    *reinterpret_cast<short8v*>(out + ((size_t)bh * HD + hd) * TDIM + t0 + tseg) = v;
  }
}

// y==0: sk = LN(k@lkw^T+lkb, lnd) -> bf16 [t][hd]; y==1: vp -> bf16 [hd][t]
__global__ __launch_bounds__(256) void headproj_kv_kernel(
    const float* __restrict__ kin, unsigned short* __restrict__ skb,
    const float* __restrict__ lkw, const float* __restrict__ lkb,
    const float* __restrict__ lnd,
    const float* __restrict__ vin, unsigned short* __restrict__ vpT,
    const float* __restrict__ lvw, const float* __restrict__ lvb)
{
  __shared__ float wl[64 * 65];
  __shared__ unsigned short tT[64 * 34];
  if (blockIdx.y == 0)
    headproj_body<0, true >(kin, skb, lkw, lkb, lnd, wl, tT);
  else
    headproj_body<1, false>(vin, vpT, lvw, lvb, (const float*)nullptr, wl, tT);
}

// ---------------------------------------------------------------------------
// MFMA flash attention, 8 waves = 4 q-strips x 2 K-halves (K-split + merge),
// KCH=64, 128B-row conflict-clean swizzled LDS, 80KB exact (2 blocks/CU).
// Fused sq-projection, defer-max, exact merge, fused epilogue, and FUSED
// state update: blocks atomically accumulate |io-prev| into accF[it]; the
// last block (ACQ_REL counter) reads accF (agent-scope atomic load, coherent
// across XCDs) and updates FState for the next dispatch.
// ---------------------------------------------------------------------------
__global__ __launch_bounds__(512) void attn_mfma_kernel(
    const float* __restrict__ qcur, const unsigned short* __restrict__ sk,
    const unsigned short* __restrict__ vpT, float* __restrict__ io,
    const float* __restrict__ prev, _Float16* __restrict__ attnH,
    const _Float16* __restrict__ lqwH, const float* __restrict__ lqb,
    const float* __restrict__ lnc, float* __restrict__ accF,
    unsigned* __restrict__ cnt, FState* __restrict__ st, int it)
{
  if (st->done) return;
  const int is_first = (it == 0);
  const int lid = blockIdx.x;
  const int xcd = lid & 7;
  const int rr_ = lid >> 3;          // 0..63
  const int qb  = rr_ & 15;          // 16 q-blocks of 64 rows
  const int bh  = (rr_ >> 4) * 8 + xcd;

  const int cw = st->cw;
  const int tid = threadIdx.x;
  const int wv = tid >> 6, lane = tid & 63;
  const int wq = wv & 3, wk = wv >> 2;       // q-strip, K-half
  const int ql = lane & 15, hi = lane >> 4;
  const int qbase = qb * 64 + wq * 16;
  const int q = qbase + ql;
  const size_t baseRow = (size_t)bh * TDIM * HD;
  const size_t baseT   = (size_t)bh * HD * TDIM;
  float* orow = io + baseRow + (size_t)q * HD;
  const float* prow = prev + baseRow + (size_t)q * HD;
  float* qcrow = const_cast<float*>(qcur) + baseRow + (size_t)q * HD;
  const bool wvalid = (qbase < cw);
  _Float16* arow = attnH + (size_t)((bh >> 4) * TDIM + q) * 1024 + (bh & 15) * HD;

  // [half][buf][K=0/V=1][8KB] (64KB). Reused after the loop: Obuf (merge)
  // and wred (diff scratch) alias dead regions. LDS total exactly 80KB.
  __shared__ __align__(16) unsigned char KV[2][2][2][8192];
  __shared__ __align__(16) unsigned char PJ[8][2048];   // per-wave P/proj (16KB)
  float* wred = reinterpret_cast<float*>(&KV[1][1][0][0]);   // aliased (dead then)

  // staging geometry (r7-proven): lane l -> row sub=l>>3 within 8-row group,
  // colByte (l&7)*16, source col XOR-swizzled by ((row&7)<<4); LDS linear.
  const int sub  = lane >> 3;
  const int colB = (lane & 7) * 16;
  const int scol = (colB ^ (sub << 4)) >> 1;

  const int kb0 = wk * 512;
  const unsigned short* kSrc0 = sk  + baseRow + (size_t)(kb0 + wq * 16 + sub) * HD + scol;
  const unsigned short* vSrc0 = vpT + baseT  + (size_t)(wq * 16 + sub) * TDIM + scol;

  unsigned char* pj = (unsigned char*)PJ[wv];
  const unsigned swz8 = (unsigned)((ql & 7) << 4);   // 128B-row swizzle (everything)

  const int nch0 = (min(cw, 512) + 63) >> 6;
  const int nch1 = (cw > 512) ? ((cw - 512 + 63) >> 6) : 0;
  const int nchOwn = wk ? nch1 : nch0;

  // ---- 1. issue chunk-0 staging for own half ----
  if (nchOwn > 0) {
#pragma unroll
    for (int jj = 0; jj < 2; ++jj) {
      gload16(kSrc0 + (size_t)(jj * 8) * HD, &KV[wk][0][0][(wq * 2 + jj) * 1024]);
      gload16(vSrc0 + (size_t)(jj * 8) * TDIM + kb0, &KV[wk][0][1][(wq * 2 + jj) * 1024]);
    }
  }

  // ---- 2. fused sq projection (r8-proven; 2KB proj region, 128B rows) ----
  short8v qf0, qf1;
  if (wvalid) {
    const float tp = st->temp;
    const float ts = (tp > 0.0f ? rsqrtf(tp) : 1.0f) * 0.125f;
    half8v qh0, qh1;
    {
      const f32x4 a0 = *reinterpret_cast<const f32x4*>(qcrow + hi * 8);
      const f32x4 a1 = *reinterpret_cast<const f32x4*>(qcrow + hi * 8 + 4);
      const f32x4 b0 = *reinterpret_cast<const f32x4*>(qcrow + 32 + hi * 8);
      const f32x4 b1 = *reinterpret_cast<const f32x4*>(qcrow + 32 + hi * 8 + 4);
#pragma unroll
      for (int j = 0; j < 4; ++j) {
        qh0[j] = (_Float16)a0[j]; qh0[4 + j] = (_Float16)a1[j];
        qh1[j] = (_Float16)b0[j]; qh1[4 + j] = (_Float16)b1[j];
      }
    }
    f32x4 sp[4];
#pragma unroll
    for (int f = 0; f < 4; ++f) {
      const half8v a0 = *reinterpret_cast<const half8v*>(lqwH + (f * 16 + ql) * 64 + hi * 8);
      const half8v a1 = *reinterpret_cast<const half8v*>(lqwH + (f * 16 + ql) * 64 + 32 + hi * 8);
      f32x4 acc = {};
      acc = __builtin_amdgcn_mfma_f32_16x16x32_f16(a0, qh0, acc, 0, 0, 0);
      acc = __builtin_amdgcn_mfma_f32_16x16x32_f16(a1, qh1, acc, 0, 0, 0);
      sp[f] = acc;
    }
    float sum = 0.f;
#pragma unroll
    for (int f = 0; f < 4; ++f) {
      const f32x4 b4 = *reinterpret_cast<const f32x4*>(lqb + f * 16 + hi * 4);
      sp[f] += b4;
      sum += (sp[f][0] + sp[f][1]) + (sp[f][2] + sp[f][3]);
    }
    sum += __shfl_xor(sum, 16);
    sum += __shfl_xor(sum, 32);
    const float mean = sum * (1.0f / 64.0f);
    float vs = 0.f;
#pragma unroll
    for (int f = 0; f < 4; ++f) {
#pragma unroll
      for (int r = 0; r < 4; ++r) {
        const float t0 = sp[f][r] - mean;
        sp[f][r] = t0;
        vs += t0 * t0;
      }
    }
    vs += __shfl_xor(vs, 16);
    vs += __shfl_xor(vs, 32);
    const float inv = rsqrtf(vs * (1.0f / 64.0f) + 1e-5f);
    const unsigned wb = (unsigned)(ql * 128 + hi * 8);
#pragma unroll
    for (int f = 0; f < 4; ++f) {
      const f32x4 lc = *reinterpret_cast<const f32x4*>(lnc + f * 16 + hi * 4);
      const float y0 = sp[f][0] * inv * lc[0] * ts;
      const float y1 = sp[f][1] * inv * lc[1] * ts;
      const float y2 = sp[f][2] * inv * lc[2] * ts;
      const float y3 = sp[f][3] * inv * lc[3] * ts;
      *reinterpret_cast<unsigned*>(pj + ((wb + f * 32)     ^ swz8)) =
          (unsigned)f2bf(y0) | ((unsigned)f2bf(y1) << 16);
      *reinterpret_cast<unsigned*>(pj + ((wb + f * 32 + 4) ^ swz8)) =
          (unsigned)f2bf(y2) | ((unsigned)f2bf(y3) << 16);
    }
    qf0 = *reinterpret_cast<short8v*>(pj + ((unsigned)(ql * 128 + hi * 16) ^ swz8));
    qf1 = *reinterpret_cast<short8v*>(pj + ((unsigned)(ql * 128 + 64 + hi * 16) ^ swz8));
  }
  __syncthreads();   // chunk-0 staged, projection done

  // ---- 3. flash loop over own half (8 chunks of 64 keys) ----
  float m = -1e30f, l = 0.f;
  f32x4 o[4] = {};
  int cur = 0;
  for (int ch = 0; ch < nch0; ++ch) {
    if (ch + 1 < nchOwn) {
      const size_t kn = (size_t)(ch + 1) * 64;
#pragma unroll
      for (int jj = 0; jj < 2; ++jj) {
        gload16(kSrc0 + (kn + (size_t)(jj * 8)) * HD, &KV[wk][cur ^ 1][0][(wq * 2 + jj) * 1024]);
        gload16(vSrc0 + (size_t)(jj * 8) * TDIM + kb0 + kn, &KV[wk][cur ^ 1][1][(wq * 2 + jj) * 1024]);
      }
    }
    if (wvalid && ch < nchOwn) {
      const int k0 = kb0 + ch * 64;
      const unsigned char* kt = &KV[wk][cur][0][0];
      const unsigned char* vt = &KV[wk][cur][1][0];
      // ---- QK^T: 4 key-frags of 16
      f32x4 s[4];
#pragma unroll
      for (int f = 0; f < 4; ++f) {
        const unsigned rb = (unsigned)((f * 16 + ql) * 128);
        const short8v a0 = *reinterpret_cast<const short8v*>(kt + rb + ((unsigned)(hi * 16) ^ swz8));
        const short8v a1 = *reinterpret_cast<const short8v*>(kt + rb + ((unsigned)(64 + hi * 16) ^ swz8));
        f32x4 acc = {};
        acc = __builtin_amdgcn_mfma_f32_16x16x32_bf16(a0, qf0, acc, 0, 0, 0);
        acc = __builtin_amdgcn_mfma_f32_16x16x32_bf16(a1, qf1, acc, 0, 0, 0);
        s[f] = acc;
      }
      // ---- chunk max (mask only on a partial last chunk)
      float mc = -1e30f;
      if (k0 + 64 > cw) {
#pragma unroll
        for (int f = 0; f < 4; ++f)
#pragma unroll
          for (int r = 0; r < 4; ++r) {
            float v = s[f][r];
            if (k0 + f * 16 + hi * 4 + r >= cw) v = -1e30f;
            s[f][r] = v;
            mc = fmaxf(mc, v);
          }
      } else {
#pragma unroll
        for (int f = 0; f < 4; ++f)
#pragma unroll
          for (int r = 0; r < 4; ++r) mc = fmaxf(mc, s[f][r]);
      }
      mc = fmaxf(mc, __shfl_xor(mc, 16));
      mc = fmaxf(mc, __shfl_xor(mc, 32));
      // defer-max: rescale only when some row's max grew past m+8
      if (__any(mc > m + 8.0f)) {
        const float mn = fmaxf(m, mc);
        const float c = __builtin_amdgcn_exp2f((m - mn) * L2E);
        l *= c;
#pragma unroll
        for (int f = 0; f < 4; ++f) o[f] *= c;
        m = mn;
      }
      // ---- exp + pack (P bounded by e^8)
      float ls = 0.f;
      unsigned pk[8];
#pragma unroll
      for (int f = 0; f < 4; ++f) {
        const float p0 = __builtin_amdgcn_exp2f((s[f][0] - m) * L2E);
        const float p1 = __builtin_amdgcn_exp2f((s[f][1] - m) * L2E);
        const float p2 = __builtin_amdgcn_exp2f((s[f][2] - m) * L2E);
        const float p3 = __builtin_amdgcn_exp2f((s[f][3] - m) * L2E);
        ls += (p0 + p1) + (p2 + p3);
        pk[f * 2]     = (unsigned)f2bf(p0) | ((unsigned)f2bf(p1) << 16);
        pk[f * 2 + 1] = (unsigned)f2bf(p2) | ((unsigned)f2bf(p3) << 16);
      }
      ls += __shfl_xor(ls, 16);
      ls += __shfl_xor(ls, 32);
      l += ls;
      // ---- P write (128B rows, swz8)
      const unsigned wb = (unsigned)(ql * 128 + hi * 8);
#pragma unroll
      for (int f = 0; f < 4; ++f) {
        *reinterpret_cast<unsigned*>(pj + ((wb + f * 32)     ^ swz8)) = pk[f * 2];
        *reinterpret_cast<unsigned*>(pj + ((wb + f * 32 + 4) ^ swz8)) = pk[f * 2 + 1];
      }
      // ---- PV: O^T[hd][q] += V^T . P^
#pragma unroll
      for (int kh = 0; kh < 2; ++kh) {
        const short8v pb = *reinterpret_cast<short8v*>(
            pj + ((unsigned)(ql * 128 + kh * 64 + hi * 16) ^ swz8));
#pragma unroll
        for (int f = 0; f < 4; ++f) {
          const unsigned rb = (unsigned)((f * 16 + ql) * 128);
          const short8v av = *reinterpret_cast<const short8v*>(
              vt + rb + ((unsigned)(kh * 64 + hi * 16) ^ swz8));
          o[f] = __builtin_amdgcn_mfma_f32_16x16x32_bf16(av, pb, o[f], 0, 0, 0);
        }
      }
    }
    __syncthreads();
    cur ^= 1;
  }

  // ---- 4. merge halves (wk=1 publishes via LDS aliased over KV) ----
  float* Obuf = reinterpret_cast<float*>(&KV[0][0][0][0]);   // [64][68] + M/L
  if (wk == 1 && wvalid) {
    if (hi == 0) {
      Obuf[4352 + wq * 16 + ql] = m;   // Mbuf
      Obuf[4416 + wq * 16 + ql] = l;   // Lbuf
    }
#pragma unroll
    for (int f = 0; f < 4; ++f)
      *reinterpret_cast<f32x4*>(&Obuf[(wq * 16 + ql) * 68 + f * 16 + hi * 4]) = o[f];
  }
  __syncthreads();

  // ---- 5. epilogue (wk=0 waves): merge, normalize, store, fused diff ----
  float pd = 0.0f;
  if (wk == 0) {
    if (wvalid) {
      const float m1 = Obuf[4352 + wq * 16 + ql];
      const float l1 = Obuf[4416 + wq * 16 + ql];
      const float mn = fmaxf(m, m1);
      const float c0 = __builtin_amdgcn_exp2f((m - mn) * L2E);
      const float c1 = __builtin_amdgcn_exp2f((m1 - mn) * L2E);
      const float lt = l * c0 + l1 * c1;
      const bool valid = (q < cw);
      const float invl = valid ? (1.0f / lt) : 0.0f;
#pragma unroll
      for (int f = 0; f < 4; ++f) {
        const f32x4 o1 = *reinterpret_cast<const f32x4*>(&Obuf[(wq * 16 + ql) * 68 + f * 16 + hi * 4]);
        const f32x4 vo = (o[f] * c0 + o1 * c1) * invl;
        *reinterpret_cast<f32x4*>(orow + f * 16 + hi * 4) = vo;
        half4v h4;
        h4[0] = (_Float16)vo[0]; h4[1] = (_Float16)vo[1];
        h4[2] = (_Float16)vo[2]; h4[3] = (_Float16)vo[3];
        *reinterpret_cast<half4v*>(arow + f * 16 + hi * 4) = h4;
        const f32x4 qv = *reinterpret_cast<const f32x4*>(qcrow + f * 16 + hi * 4);
        *reinterpret_cast<f32x4*>(qcrow + f * 16 + hi * 4) = qv + vo;
        if (!is_first) {
          const f32x4 pv = *reinterpret_cast<const f32x4*>(prow + f * 16 + hi * 4);
          pd += fabsf(vo[0] - pv[0]) + fabsf(vo[1] - pv[1]) +
                fabsf(vo[2] - pv[2]) + fabsf(vo[3] - pv[3]);
        } else {
          pd += fabsf(vo[0]) + fabsf(vo[1]) + fabsf(vo[2]) + fabsf(vo[3]);
        }
      }
    } else {
      const f32x4 z = {0.f, 0.f, 0.f, 0.f};
      const half4v hz = { (_Float16)0.f, (_Float16)0.f, (_Float16)0.f, (_Float16)0.f };
#pragma unroll
      for (int f = 0; f < 4; ++f) {
        *reinterpret_cast<f32x4*>(orow + f * 16 + hi * 4) = z;
        *reinterpret_cast<half4v*>(arow + f * 16 + hi * 4) = hz;
        if (!is_first) {
          const f32x4 pv = *reinterpret_cast<const f32x4*>(prow + f * 16 + hi * 4);
          pd += fabsf(pv[0]) + fabsf(pv[1]) + fabsf(pv[2]) + fabsf(pv[3]);
        }
      }
    }
  }

#pragma unroll
  for (int off = 1; off < 64; off <<= 1) pd += __shfl_xor(pd, off);
  if (lane == 0) wred[wv] = pd;
  __syncthreads();

  // ---- 6. fused state update (last-block pattern, agent-scope atomics) ----
  if (tid == 0) {
    const float blockSum = wred[0] + wred[1] + wred[2] + wred[3] +
                           wred[4] + wred[5] + wred[6] + wred[7];
    __hip_atomic_fetch_add(&accF[it], blockSum, __ATOMIC_RELAXED,
                           __HIP_MEMORY_SCOPE_AGENT);
    const unsigned old = __hip_atomic_fetch_add(&cnt[it], 1u, __ATOMIC_ACQ_REL,
                                                __HIP_MEMORY_SCOPE_AGENT);
    if (old == DIFF_BLOCKS - 1) {
      const float total = __hip_atomic_load(&accF[it], __ATOMIC_ACQUIRE,
                                            __HIP_MEMORY_SCOPE_AGENT);
      const float diff = total * (1.0f / (float)NHE);
      const bool conv = (diff < st->thr + st->fac * diff) && (it > 0);
      st->done = conv ? 1 : 0;
      if (!conv) {
        const int cwv = st->cw;
        const int up = (int)((float)cwv * 1.1f);
        const int dn = (int)((float)cwv * 0.9f);
        int nw = (diff > 0.05f) ? up : ((diff < 0.001f && cwv > 64) ? dn : cwv);
        nw = nw < 64 ? 64 : (nw > TDIM ? TDIM : nw);
        st->cw = nw;
        st->temp += 0.005f;
      }
    }
  }
}

// ---------------------------------------------------------------------------
extern "C" void kernel_launch(void* const* d_in, const int* in_sizes, int n_in,
                              void* d_out, int out_size, void* d_ws, size_t ws_size,
                              hipStream_t stream)
{
  const float* x   = (const float*)d_in[0];
  const float* Wq  = (const float*)d_in[1];
  const float* bq  = (const float*)d_in[2];
  const float* Wk  = (const float*)d_in[3];
  const float* Wv  = (const float*)d_in[4];
  const float* bv  = (const float*)d_in[5];
  const float* Wo  = (const float*)d_in[6];
  const float* bo  = (const float*)d_in[7];
  const float* lna = (const float*)d_in[8];
  const float* lnb = (const float*)d_in[9];
  const float* lnc = (const float*)d_in[10];
  const float* lnd = (const float*)d_in[11];
  const float* lqw = (const float*)d_in[12];
  const float* lqb = (const float*)d_in[13];
  const float* lkw = (const float*)d_in[14];
  const float* lkb = (const float*)d_in[15];
  const float* lvw = (const float*)d_in[16];
  const float* lvb = (const float*)d_in[17];
  const float* thr = (const float*)d_in[18];
  const float* tb  = (const float*)d_in[19];
  const float* fac = (const float*)d_in[20];
  float* out = (float*)d_out;

  // workspace layout (~52 MB)
  float* f0   = (float*)d_ws;
  float* qcur = f0;                       // f32 head layout, 8MB (in-place updated)
  float* io0  = f0 + (size_t)NHE;         // f32 (k-heads temp, then iter_out ping)
  float* io1  = f0 + 2 * (size_t)NHE;     // f32 (v-heads temp, then iter_out pong)
  _Float16* h0   = (_Float16*)(f0 + 3 * (size_t)NHE);
  _Float16* xaH  = h0;                         // [2048][1024] fp16 (aliases attnH)
  _Float16* attnH = h0;
  _Float16* xbH  = h0 + (size_t)RROWS * 1024;
  _Float16* WqH  = xbH + (size_t)RROWS * 1024; // [1024][1024] fp16 each
  _Float16* WkH  = WqH + (size_t)1048576;
  _Float16* WvH  = WkH + (size_t)1048576;
  _Float16* WoH  = WvH + (size_t)1048576;
  _Float16* lqwH = WoH + (size_t)1048576;      // [64][64] fp16
  unsigned short* skb = (unsigned short*)(lqwH + 4096);  // bf16 [bh][t][hd]
  unsigned short* vpT = skb + (size_t)NHE;               // bf16 [bh][hd][t]
  float* accF = (float*)(vpT + (size_t)NHE);             // [3] diff accumulators
  unsigned* cnt = (unsigned*)(accF + 4);                 // [3] block counters
  FState* st = (FState*)(cnt + 4);

  constexpr float SC = 0.35355339059327379f;  // 64^-0.25

  // prep: init + LN(x) + weight conversion in one launch
  hipLaunchKernelGGL(prep_kernel, dim3(6149), dim3(256), 0, stream,
                     x, lna, lnb, xaH, xbH,
                     Wq, Wk, Wv, Wo, lqw, WqH, WkH, WvH, WoH, lqwH,
                     st, accF, cnt, thr, tb, fac);

  // fused QKV fp16 MFMA GEMMs -> f32 head layouts (qcur, io0=k, io1=v)
  hipLaunchKernelGGL((gemm_mfma_kernel<1>), dim3(16, 16, 3), dim3(256), 0, stream,
                     xaH, WqH, bq, qcur, SC,
                     xbH, WkH, (const float*)nullptr, io0, SC,
                     xbH, WvH, bv, io1, 1.0f);

  // iteration-invariant head projections (k -> skb, v -> vpT) in one launch
  hipLaunchKernelGGL(headproj_kv_kernel, dim3(1024, 2), dim3(256), 0, stream,
                     io0, skb, lkw, lkb, lnd, io1, vpT, lvw, lvb);

  for (int it = 0; it < 3; ++it) {
    float* io   = (it & 1) ? io1 : io0;
    float* prev = (it & 1) ? io0 : io1;
    hipLaunchKernelGGL(attn_mfma_kernel, dim3(DIFF_BLOCKS), dim3(512), 0, stream,
                       qcur, skb, vpT, io, prev, attnH, lqwH, lqb, lnc,
                       accF, cnt, st, it);
  }

  // final fp16 MFMA GEMM: out = attn @ Wo^T + bo (row-major f32)
  hipLaunchKernelGGL((gemm_mfma_kernel<0>), dim3(16, 16, 1), dim3(256), 0, stream,
                     attnH, WoH, bo, out, 1.0f,
                     attnH, WoH, bo, out, 1.0f,
                     attnH, WoH, bo, out, 1.0f);
}

// Round 13
// 154.230 us; speedup vs baseline: 1.0804x; 1.0804x over previous
//
#include <hip/hip_runtime.h>
#include <hip/hip_bf16.h>

// Sizes (fixed by the reference)
#define BDIM 2
#define TDIM 1024
#define DDIM 1024
#define HDIM 16
#define HD   64
#define RROWS (BDIM * TDIM)        // 2048 rows for the big GEMMs
#define BH    (BDIM * HDIM)        // 32 (b,h) pairs
#define NHE   (BH * TDIM * HD)     // 2,097,152 elements in head layout
#define NHE4  (NHE / 4)
#define DIFF_BLOCKS 512            // = attn grid (16 qb x 32 bh)
#define L2E 1.4426950408889634f

typedef __attribute__((ext_vector_type(8))) short short8v;
typedef __attribute__((ext_vector_type(4))) short short4v;
typedef __attribute__((ext_vector_type(8))) _Float16 half8v;
typedef __attribute__((ext_vector_type(4))) _Float16 half4v;
typedef __attribute__((ext_vector_type(4))) float f32x4;

struct FState {
  int   cw;
  float temp;
  int   done;
  int   upd;
  int   done_prev;
  float thr;
  float fac;
  int   pad;
};

static __device__ __forceinline__ unsigned short f2bf(float x) {
  __hip_bfloat16 h = __float2bfloat16(x);
  return __builtin_bit_cast(unsigned short, h);
}
// async global->LDS, 16B per lane. LDS dest is wave-uniform base (+lane*16 by HW).
static __device__ __forceinline__ void gload16(const void* g, void* l) {
  __builtin_amdgcn_global_load_lds(
      (const __attribute__((address_space(1))) void*)g,
      (__attribute__((address_space(3))) void*)l, 16, 0, 0);
}

// ---------------------------------------------------------------------------
// prep: one launch = init state + LN(x) (fp16) + weight f32->fp16.
// 1-D grid, range-decoded: [0,2048) ln rows; [2048,6144) big-W rows;
// [6144,6148) lqw rows; 6148 init.
// ---------------------------------------------------------------------------
__global__ __launch_bounds__(256) void prep_kernel(
    const float* __restrict__ x, const float* __restrict__ wa, const float* __restrict__ wb,
    _Float16* __restrict__ xaH, _Float16* __restrict__ xbH,
    const float* __restrict__ W0, const float* __restrict__ W1,
    const float* __restrict__ W2, const float* __restrict__ W3,
    const float* __restrict__ W4,
    _Float16* __restrict__ O0, _Float16* __restrict__ O1,
    _Float16* __restrict__ O2, _Float16* __restrict__ O3,
    _Float16* __restrict__ O4,
    FState* st, const float* thr, const float* tb, const float* fac)
{
  const int bid = blockIdx.x;
  const int tid = threadIdx.x;

  if (bid >= 6148) {                       // ---- init ----
    if (tid == 0) {
      st->cw = TDIM;
      st->temp = tb[0];
      st->done = 0;
      st->done_prev = 0;
      st->upd = 1;
      st->thr = thr[0];
      st->fac = fac[0];
    }
    return;
  }

  if (bid >= 2048) {                       // ---- weight convert ----
    const int idx = bid - 2048;
    const float* W; _Float16* O; int r;
    if (bid >= 6144) { W = W4; O = O4; r = bid - 6144; }
    else {
      const int mat = idx >> 10;
      r = idx & 1023;
      switch (mat) {
        case 0:  W = W0; O = O0; break;
        case 1:  W = W1; O = O1; break;
        case 2:  W = W2; O = O2; break;
        default: W = W3; O = O3; break;
      }
    }
    const float4 v = reinterpret_cast<const float4*>(W + (size_t)r * 1024)[tid];
    half4v h;
    h[0] = (_Float16)v.x; h[1] = (_Float16)v.y;
    h[2] = (_Float16)v.z; h[3] = (_Float16)v.w;
    *reinterpret_cast<half4v*>(O + (size_t)r * 1024 + tid * 4) = h;
    return;
  }

  // ---- LayerNorm of x (shared mean/var, two weights) ----
  const int row = bid;
  const float4 v = reinterpret_cast<const float4*>(x + (size_t)row * DDIM)[tid];
  float s = v.x + v.y + v.z + v.w;
  float q = v.x * v.x + v.y * v.y + v.z * v.z + v.w * v.w;
#pragma unroll
  for (int off = 1; off < 64; off <<= 1) {
    s += __shfl_xor(s, off);
    q += __shfl_xor(q, off);
  }
  __shared__ float ss[4], qq[4];
  const int lane = tid & 63, wv = tid >> 6;
  if (lane == 0) { ss[wv] = s; qq[wv] = q; }
  __syncthreads();
  s = ss[0] + ss[1] + ss[2] + ss[3];
  q = qq[0] + qq[1] + qq[2] + qq[3];
  const float mean = s * (1.0f / DDIM);
  const float var  = q * (1.0f / DDIM) - mean * mean;
  const float inv  = rsqrtf(var + 1e-5f);
  const float4 a4 = reinterpret_cast<const float4*>(wa)[tid];
  const float4 b4 = reinterpret_cast<const float4*>(wb)[tid];
  const float hv[4] = { (v.x - mean) * inv, (v.y - mean) * inv,
                        (v.z - mean) * inv, (v.w - mean) * inv };
  const float av[4] = { a4.x, a4.y, a4.z, a4.w };
  const float bv[4] = { b4.x, b4.y, b4.z, b4.w };
  half4v ha, hb;
#pragma unroll
  for (int j = 0; j < 4; ++j) {
    ha[j] = (_Float16)(hv[j] * av[j]);
    hb[j] = (_Float16)(hv[j] * bv[j]);
  }
  *reinterpret_cast<half4v*>(xaH + (size_t)row * DDIM + tid * 4) = ha;
  *reinterpret_cast<half4v*>(xbH + (size_t)row * DDIM + tid * 4) = hb;
}

// ---------------------------------------------------------------------------
// fp16 MFMA GEMM: C = (A @ W^T + bias) * scale, fp32 accumulation.
// 128x128 tile, BK=32, 4 waves (2x2), 4x4 16x16x32 frags per wave (r11-proven).
// ---------------------------------------------------------------------------
template<int CMODE>
__global__ __launch_bounds__(256) void gemm_mfma_kernel(
    const _Float16* __restrict__ A0, const _Float16* __restrict__ W0,
    const float* __restrict__ b0, float* __restrict__ C0, float s0,
    const _Float16* __restrict__ A1, const _Float16* __restrict__ W1,
    const float* __restrict__ b1, float* __restrict__ C1, float s1,
    const _Float16* __restrict__ A2, const _Float16* __restrict__ W2,
    const float* __restrict__ b2, float* __restrict__ C2, float s2)
{
  const _Float16* A; const _Float16* W; const float* bias; float* C; float scale;
  switch (blockIdx.z) {
    case 0:  A = A0; W = W0; bias = b0; C = C0; scale = s0; break;
    case 1:  A = A1; W = W1; bias = b1; C = C1; scale = s1; break;
    default: A = A2; W = W2; bias = b2; C = C2; scale = s2; break;
  }
  __shared__ __align__(16) _Float16 As[128 * 32];
  __shared__ __align__(16) _Float16 Ws[128 * 32];
  const int tid = threadIdx.x;
  const int wv = tid >> 6, lane = tid & 63;
  const int wm = wv >> 1, wn = wv & 1;
  const int bm = blockIdx.x;           // 16 M-blocks
  const int bn = blockIdx.y;           // 8 N-blocks

  const _Float16* gA[2]; const _Float16* gW[2];
  _Float16* lA[2]; _Float16* lW[2];
#pragma unroll
  for (int j = 0; j < 2; ++j) {
    const int chunk = wv * 2 + j;                  // 0..7
    const int r = chunk * 16 + (lane >> 2);
    const int ce = (lane & 3) * 8;                 // element col within 32
    gA[j] = A + (size_t)(bm * 128 + r) * 1024 + ce;
    gW[j] = W + (size_t)(bn * 128 + r) * 1024 + ce;
    lA[j] = As + chunk * 512;                      // wave-uniform base
    lW[j] = Ws + chunk * 512;
  }

  f32x4 acc[4][4] = {};
  const int rb = lane & 15;
  const int kb = (lane >> 4) * 8;

  for (int ks = 0; ks < 1024; ks += 32) {
    __syncthreads();
#pragma unroll
    for (int j = 0; j < 2; ++j) {
      gload16(gA[j] + ks, lA[j]);
      gload16(gW[j] + ks, lW[j]);
    }
    __syncthreads();
    half8v af[4], wf[4];
#pragma unroll
    for (int f = 0; f < 4; ++f) {
      af[f] = *reinterpret_cast<const half8v*>(As + (wm * 64 + f * 16 + rb) * 32 + kb);
      wf[f] = *reinterpret_cast<const half8v*>(Ws + (wn * 64 + f * 16 + rb) * 32 + kb);
    }
#pragma unroll
    for (int i = 0; i < 4; ++i)
#pragma unroll
      for (int j2 = 0; j2 < 4; ++j2)
        acc[i][j2] = __builtin_amdgcn_mfma_f32_16x16x32_f16(af[i], wf[j2], acc[i][j2], 0, 0, 0);
  }

#pragma unroll
  for (int j2 = 0; j2 < 4; ++j2) {
    const int n = bn * 128 + wn * 64 + j2 * 16 + (lane & 15);
    const float bv_ = bias ? bias[n] : 0.0f;
#pragma unroll
    for (int i = 0; i < 4; ++i) {
#pragma unroll
      for (int r = 0; r < 4; ++r) {
        const int m = bm * 128 + wm * 64 + i * 16 + (lane >> 4) * 4 + r;
        const float v = (acc[i][j2][r] + bv_) * scale;
        size_t ci;
        if constexpr (CMODE == 0) {
          ci = (size_t)m * 1024 + n;
        } else {
          const int b = m >> 10, t = m & (TDIM - 1);
          ci = ((size_t)(b * HDIM + (n >> 6)) * TDIM + t) * HD + (n & 63);
        }
        C[ci] = v;
      }
    }
  }
}

// ---------------------------------------------------------------------------
// per-head 64x64 projection body (iteration-invariant k/v paths)
// ---------------------------------------------------------------------------
template<int OUT_MODE, bool DO_LN>
static __device__ __forceinline__ void headproj_body(
    const float* __restrict__ in, unsigned short* __restrict__ out,
    const float* __restrict__ w, const float* __restrict__ bias,
    const float* __restrict__ lnw, float* wl, unsigned short* tT)
{
  const int tid = threadIdx.x;
  for (int idx = tid; idx < 4096; idx += 256) {
    const int d = idx >> 6, i = idx & 63;
    wl[i * 65 + d] = w[idx];
  }
  const int lane = tid & 63, wv = tid >> 6;
  const float bd = bias[lane];
  float lw = 1.0f;
  if constexpr (DO_LN) lw = lnw[lane];
  __syncthreads();
  const int rowBase = blockIdx.x * 32 + wv * 8;
  for (int rr = 0; rr < 8; ++rr) {
    const int row = rowBase + rr;
    const float h = in[(size_t)row * HD + lane];
    float y = bd;
#pragma unroll
    for (int i = 0; i < 64; ++i) {
      const float hv = __uint_as_float((unsigned)__builtin_amdgcn_readlane((int)__float_as_uint(h), i));
      y += wl[i * 65 + lane] * hv;
    }
    if constexpr (DO_LN) {
      float s = y;
#pragma unroll
      for (int off = 1; off < 64; off <<= 1) s += __shfl_xor(s, off);
      const float mean = s * (1.0f / 64.0f);
      const float t0 = y - mean;
      float v2 = t0 * t0;
#pragma unroll
      for (int off = 1; off < 64; off <<= 1) v2 += __shfl_xor(v2, off);
      y = t0 * rsqrtf(v2 * (1.0f / 64.0f) + 1e-5f) * lw;
    }
    if constexpr (OUT_MODE == 0) {
      out[(size_t)row * HD + lane] = f2bf(y);
    } else {
      tT[lane * 34 + wv * 8 + rr] = f2bf(y);
    }
  }
  if constexpr (OUT_MODE == 1) {
    __syncthreads();
    const int hd = tid >> 2, tseg = (tid & 3) * 8;
    const int r0 = blockIdx.x * 32;
    const int bh = r0 >> 10, t0 = r0 & (TDIM - 1);
    short8v v;
#pragma unroll
    for (int i = 0; i < 8; ++i) v[i] = (short)tT[hd * 34 + tseg + i];
    *reinterpret_cast<short8v*>(out + ((size_t)bh * HD + hd) * TDIM + t0 + tseg) = v;
  }
}

// y==0: sk = LN(k@lkw^T+lkb, lnd) -> bf16 [t][hd]; y==1: vp -> bf16 [hd][t]
__global__ __launch_bounds__(256) void headproj_kv_kernel(
    const float* __restrict__ kin, unsigned short* __restrict__ skb,
    const float* __restrict__ lkw, const float* __restrict__ lkb,
    const float* __restrict__ lnd,
    const float* __restrict__ vin, unsigned short* __restrict__ vpT,
    const float* __restrict__ lvw, const float* __restrict__ lvb)
{
  __shared__ float wl[64 * 65];
  __shared__ unsigned short tT[64 * 34];
  if (blockIdx.y == 0)
    headproj_body<0, true >(kin, skb, lkw, lkb, lnd, wl, tT);
  else
    headproj_body<1, false>(vin, vpT, lvw, lvb, (const float*)nullptr, wl, tT);
}

// ---------------------------------------------------------------------------
// MFMA flash attention, 8 waves = 4 q-strips x 2 K-halves (K-split + merge),
// KCH=64, 128B-row conflict-clean swizzled LDS, 80KB exact (2 blocks/CU).
// Fused sq-projection, defer-max, exact merge, fused epilogue (io, attnH,
// qcur+=, |io-prev| diff -> partials). s_setprio(1) around MFMA clusters
// (T5: waves are at different phases -> scheduler arbitration pays).
// ---------------------------------------------------------------------------
__global__ __launch_bounds__(512) void attn_mfma_kernel(
    const float* __restrict__ qcur, const unsigned short* __restrict__ sk,
    const unsigned short* __restrict__ vpT, float* __restrict__ io,
    const float* __restrict__ prev, _Float16* __restrict__ attnH,
    const _Float16* __restrict__ lqwH, const float* __restrict__ lqb,
    const float* __restrict__ lnc, float* __restrict__ partials,
    const FState* __restrict__ st, int is_first)
{
  if (st->done) return;
  const int lid = blockIdx.x;
  const int xcd = lid & 7;
  const int rr_ = lid >> 3;          // 0..63
  const int qb  = rr_ & 15;          // 16 q-blocks of 64 rows
  const int bh  = (rr_ >> 4) * 8 + xcd;

  const int cw = st->cw;
  const int tid = threadIdx.x;
  const int wv = tid >> 6, lane = tid & 63;
  const int wq = wv & 3, wk = wv >> 2;       // q-strip, K-half
  const int ql = lane & 15, hi = lane >> 4;
  const int qbase = qb * 64 + wq * 16;
  const int q = qbase + ql;
  const size_t baseRow = (size_t)bh * TDIM * HD;
  const size_t baseT   = (size_t)bh * HD * TDIM;
  float* orow = io + baseRow + (size_t)q * HD;
  const float* prow = prev + baseRow + (size_t)q * HD;
  float* qcrow = const_cast<float*>(qcur) + baseRow + (size_t)q * HD;
  const bool wvalid = (qbase < cw);
  _Float16* arow = attnH + (size_t)((bh >> 4) * TDIM + q) * 1024 + (bh & 15) * HD;

  // [half][buf][K=0/V=1][8KB] (64KB). Reused after the loop: Obuf (merge)
  // and wred (diff scratch) alias dead regions. LDS total exactly 80KB.
  __shared__ __align__(16) unsigned char KV[2][2][2][8192];
  __shared__ __align__(16) unsigned char PJ[8][2048];   // per-wave P/proj (16KB)
  float* wred = reinterpret_cast<float*>(&KV[1][1][0][0]);   // aliased (dead then)

  // staging geometry (r7-proven): lane l -> row sub=l>>3 within 8-row group,
  // colByte (l&7)*16, source col XOR-swizzled by ((row&7)<<4); LDS linear.
  const int sub  = lane >> 3;
  const int colB = (lane & 7) * 16;
  const int scol = (colB ^ (sub << 4)) >> 1;

  const int kb0 = wk * 512;
  const unsigned short* kSrc0 = sk  + baseRow + (size_t)(kb0 + wq * 16 + sub) * HD + scol;
  const unsigned short* vSrc0 = vpT + baseT  + (size_t)(wq * 16 + sub) * TDIM + scol;

  unsigned char* pj = (unsigned char*)PJ[wv];
  const unsigned swz8 = (unsigned)((ql & 7) << 4);   // 128B-row swizzle (everything)

  const int nch0 = (min(cw, 512) + 63) >> 6;
  const int nch1 = (cw > 512) ? ((cw - 512 + 63) >> 6) : 0;
  const int nchOwn = wk ? nch1 : nch0;

  // ---- 1. issue chunk-0 staging for own half ----
  if (nchOwn > 0) {
#pragma unroll
    for (int jj = 0; jj < 2; ++jj) {
      gload16(kSrc0 + (size_t)(jj * 8) * HD, &KV[wk][0][0][(wq * 2 + jj) * 1024]);
      gload16(vSrc0 + (size_t)(jj * 8) * TDIM + kb0, &KV[wk][0][1][(wq * 2 + jj) * 1024]);
    }
  }

  // ---- 2. fused sq projection (r8-proven; 2KB proj region, 128B rows) ----
  short8v qf0, qf1;
  if (wvalid) {
    const float tp = st->temp;
    const float ts = (tp > 0.0f ? rsqrtf(tp) : 1.0f) * 0.125f;
    half8v qh0, qh1;
    {
      const f32x4 a0 = *reinterpret_cast<const f32x4*>(qcrow + hi * 8);
      const f32x4 a1 = *reinterpret_cast<const f32x4*>(qcrow + hi * 8 + 4);
      const f32x4 b0 = *reinterpret_cast<const f32x4*>(qcrow + 32 + hi * 8);
      const f32x4 b1 = *reinterpret_cast<const f32x4*>(qcrow + 32 + hi * 8 + 4);
#pragma unroll
      for (int j = 0; j < 4; ++j) {
        qh0[j] = (_Float16)a0[j]; qh0[4 + j] = (_Float16)a1[j];
        qh1[j] = (_Float16)b0[j]; qh1[4 + j] = (_Float16)b1[j];
      }
    }
    f32x4 sp[4];
#pragma unroll
    for (int f = 0; f < 4; ++f) {
      const half8v a0 = *reinterpret_cast<const half8v*>(lqwH + (f * 16 + ql) * 64 + hi * 8);
      const half8v a1 = *reinterpret_cast<const half8v*>(lqwH + (f * 16 + ql) * 64 + 32 + hi * 8);
      f32x4 acc = {};
      acc = __builtin_amdgcn_mfma_f32_16x16x32_f16(a0, qh0, acc, 0, 0, 0);
      acc = __builtin_amdgcn_mfma_f32_16x16x32_f16(a1, qh1, acc, 0, 0, 0);
      sp[f] = acc;
    }
    float sum = 0.f;
#pragma unroll
    for (int f = 0; f < 4; ++f) {
      const f32x4 b4 = *reinterpret_cast<const f32x4*>(lqb + f * 16 + hi * 4);
      sp[f] += b4;
      sum += (sp[f][0] + sp[f][1]) + (sp[f][2] + sp[f][3]);
    }
    sum += __shfl_xor(sum, 16);
    sum += __shfl_xor(sum, 32);
    const float mean = sum * (1.0f / 64.0f);
    float vs = 0.f;
#pragma unroll
    for (int f = 0; f < 4; ++f) {
#pragma unroll
      for (int r = 0; r < 4; ++r) {
        const float t0 = sp[f][r] - mean;
        sp[f][r] = t0;
        vs += t0 * t0;
      }
    }
    vs += __shfl_xor(vs, 16);
    vs += __shfl_xor(vs, 32);
    const float inv = rsqrtf(vs * (1.0f / 64.0f) + 1e-5f);
    const unsigned wb = (unsigned)(ql * 128 + hi * 8);
#pragma unroll
    for (int f = 0; f < 4; ++f) {
      const f32x4 lc = *reinterpret_cast<const f32x4*>(lnc + f * 16 + hi * 4);
      const float y0 = sp[f][0] * inv * lc[0] * ts;
      const float y1 = sp[f][1] * inv * lc[1] * ts;
      const float y2 = sp[f][2] * inv * lc[2] * ts;
      const float y3 = sp[f][3] * inv * lc[3] * ts;
      *reinterpret_cast<unsigned*>(pj + ((wb + f * 32)     ^ swz8)) =
          (unsigned)f2bf(y0) | ((unsigned)f2bf(y1) << 16);
      *reinterpret_cast<unsigned*>(pj + ((wb + f * 32 + 4) ^ swz8)) =
          (unsigned)f2bf(y2) | ((unsigned)f2bf(y3) << 16);
    }
    qf0 = *reinterpret_cast<short8v*>(pj + ((unsigned)(ql * 128 + hi * 16) ^ swz8));
    qf1 = *reinterpret_cast<short8v*>(pj + ((unsigned)(ql * 128 + 64 + hi * 16) ^ swz8));
  }
  __syncthreads();   // chunk-0 staged, projection done

  // ---- 3. flash loop over own half (8 chunks of 64 keys) ----
  float m = -1e30f, l = 0.f;
  f32x4 o[4] = {};
  int cur = 0;
  for (int ch = 0; ch < nch0; ++ch) {
    if (ch + 1 < nchOwn) {
      const size_t kn = (size_t)(ch + 1) * 64;
#pragma unroll
      for (int jj = 0; jj < 2; ++jj) {
        gload16(kSrc0 + (kn + (size_t)(jj * 8)) * HD, &KV[wk][cur ^ 1][0][(wq * 2 + jj) * 1024]);
        gload16(vSrc0 + (size_t)(jj * 8) * TDIM + kb0 + kn, &KV[wk][cur ^ 1][1][(wq * 2 + jj) * 1024]);
      }
    }
    if (wvalid && ch < nchOwn) {
      const int k0 = kb0 + ch * 64;
      const unsigned char* kt = &KV[wk][cur][0][0];
      const unsigned char* vt = &KV[wk][cur][1][0];
      // ---- QK^T: 4 key-frags of 16 (MFMA cluster, elevated priority)
      f32x4 s[4];
      __builtin_amdgcn_s_setprio(1);
#pragma unroll
      for (int f = 0; f < 4; ++f) {
        const unsigned rb = (unsigned)((f * 16 + ql) * 128);
        const short8v a0 = *reinterpret_cast<const short8v*>(kt + rb + ((unsigned)(hi * 16) ^ swz8));
        const short8v a1 = *reinterpret_cast<const short8v*>(kt + rb + ((unsigned)(64 + hi * 16) ^ swz8));
        f32x4 acc = {};
        acc = __builtin_amdgcn_mfma_f32_16x16x32_bf16(a0, qf0, acc, 0, 0, 0);
        acc = __builtin_amdgcn_mfma_f32_16x16x32_bf16(a1, qf1, acc, 0, 0, 0);
        s[f] = acc;
      }
      __builtin_amdgcn_s_setprio(0);
      // ---- chunk max (mask only on a partial last chunk)
      float mc = -1e30f;
      if (k0 + 64 > cw) {
#pragma unroll
        for (int f = 0; f < 4; ++f)
#pragma unroll
          for (int r = 0; r < 4; ++r) {
            float v = s[f][r];
            if (k0 + f * 16 + hi * 4 + r >= cw) v = -1e30f;
            s[f][r] = v;
            mc = fmaxf(mc, v);
          }
      } else {
#pragma unroll
        for (int f = 0; f < 4; ++f)
#pragma unroll
          for (int r = 0; r < 4; ++r) mc = fmaxf(mc, s[f][r]);
      }
      mc = fmaxf(mc, __shfl_xor(mc, 16));
      mc = fmaxf(mc, __shfl_xor(mc, 32));
      // defer-max: rescale only when some row's max grew past m+8
      if (__any(mc > m + 8.0f)) {
        const float mn = fmaxf(m, mc);
        const float c = __builtin_amdgcn_exp2f((m - mn) * L2E);
        l *= c;
#pragma unroll
        for (int f = 0; f < 4; ++f) o[f] *= c;
        m = mn;
      }
      // ---- exp + pack (P bounded by e^8)
      float ls = 0.f;
      unsigned pk[8];
#pragma unroll
      for (int f = 0; f < 4; ++f) {
        const float p0 = __builtin_amdgcn_exp2f((s[f][0] - m) * L2E);
        const float p1 = __builtin_amdgcn_exp2f((s[f][1] - m) * L2E);
        const float p2 = __builtin_amdgcn_exp2f((s[f][2] - m) * L2E);
        const float p3 = __builtin_amdgcn_exp2f((s[f][3] - m) * L2E);
        ls += (p0 + p1) + (p2 + p3);
        pk[f * 2]     = (unsigned)f2bf(p0) | ((unsigned)f2bf(p1) << 16);
        pk[f * 2 + 1] = (unsigned)f2bf(p2) | ((unsigned)f2bf(p3) << 16);
      }
      ls += __shfl_xor(ls, 16);
      ls += __shfl_xor(ls, 32);
      l += ls;
      // ---- P write (128B rows, swz8)
      const unsigned wb = (unsigned)(ql * 128 + hi * 8);
#pragma unroll
      for (int f = 0; f < 4; ++f) {
        *reinterpret_cast<unsigned*>(pj + ((wb + f * 32)     ^ swz8)) = pk[f * 2];
        *reinterpret_cast<unsigned*>(pj + ((wb + f * 32 + 4) ^ swz8)) = pk[f * 2 + 1];
      }
      // ---- PV: O^T[hd][q] += V^T . P^ (MFMA cluster, elevated priority)
      __builtin_amdgcn_s_setprio(1);
#pragma unroll
      for (int kh = 0; kh < 2; ++kh) {
        const short8v pb = *reinterpret_cast<short8v*>(
            pj + ((unsigned)(ql * 128 + kh * 64 + hi * 16) ^ swz8));
#pragma unroll
        for (int f = 0; f < 4; ++f) {
          const unsigned rb = (unsigned)((f * 16 + ql) * 128);
          const short8v av = *reinterpret_cast<const short8v*>(
              vt + rb + ((unsigned)(kh * 64 + hi * 16) ^ swz8));
          o[f] = __builtin_amdgcn_mfma_f32_16x16x32_bf16(av, pb, o[f], 0, 0, 0);
        }
      }
      __builtin_amdgcn_s_setprio(0);
    }
    __syncthreads();
    cur ^= 1;
  }

  // ---- 4. merge halves (wk=1 publishes via LDS aliased over KV) ----
  float* Obuf = reinterpret_cast<float*>(&KV[0][0][0][0]);   // [64][68] + M/L
  if (wk == 1 && wvalid) {
    if (hi == 0) {
      Obuf[4352 + wq * 16 + ql] = m;   // Mbuf
      Obuf[4416 + wq * 16 + ql] = l;   // Lbuf
    }
#pragma unroll
    for (int f = 0; f < 4; ++f)
      *reinterpret_cast<f32x4*>(&Obuf[(wq * 16 + ql) * 68 + f * 16 + hi * 4]) = o[f];
  }
  __syncthreads();

  // ---- 5. epilogue (wk=0 waves): merge, normalize, store, fused diff ----
  float pd = 0.0f;
  if (wk == 0) {
    if (wvalid) {
      const float m1 = Obuf[4352 + wq * 16 + ql];
      const float l1 = Obuf[4416 + wq * 16 + ql];
      const float mn = fmaxf(m, m1);
      const float c0 = __builtin_amdgcn_exp2f((m - mn) * L2E);
      const float c1 = __builtin_amdgcn_exp2f((m1 - mn) * L2E);
      const float lt = l * c0 + l1 * c1;
      const bool valid = (q < cw);
      const float invl = valid ? (1.0f / lt) : 0.0f;
#pragma unroll
      for (int f = 0; f < 4; ++f) {
        const f32x4 o1 = *reinterpret_cast<const f32x4*>(&Obuf[(wq * 16 + ql) * 68 + f * 16 + hi * 4]);
        const f32x4 vo = (o[f] * c0 + o1 * c1) * invl;
        *reinterpret_cast<f32x4*>(orow + f * 16 + hi * 4) = vo;
        half4v h4;
        h4[0] = (_Float16)vo[0]; h4[1] = (_Float16)vo[1];
        h4[2] = (_Float16)vo[2]; h4[3] = (_Float16)vo[3];
        *reinterpret_cast<half4v*>(arow + f * 16 + hi * 4) = h4;
        const f32x4 qv = *reinterpret_cast<const f32x4*>(qcrow + f * 16 + hi * 4);
        *reinterpret_cast<f32x4*>(qcrow + f * 16 + hi * 4) = qv + vo;
        if (!is_first) {
          const f32x4 pv = *reinterpret_cast<const f32x4*>(prow + f * 16 + hi * 4);
          pd += fabsf(vo[0] - pv[0]) + fabsf(vo[1] - pv[1]) +
                fabsf(vo[2] - pv[2]) + fabsf(vo[3] - pv[3]);
        } else {
          pd += fabsf(vo[0]) + fabsf(vo[1]) + fabsf(vo[2]) + fabsf(vo[3]);
        }
      }
    } else {
      const f32x4 z = {0.f, 0.f, 0.f, 0.f};
      const half4v hz = { (_Float16)0.f, (_Float16)0.f, (_Float16)0.f, (_Float16)0.f };
#pragma unroll
      for (int f = 0; f < 4; ++f) {
        *reinterpret_cast<f32x4*>(orow + f * 16 + hi * 4) = z;
        *reinterpret_cast<half4v*>(arow + f * 16 + hi * 4) = hz;
        if (!is_first) {
          const f32x4 pv = *reinterpret_cast<const f32x4*>(prow + f * 16 + hi * 4);
          pd += fabsf(pv[0]) + fabsf(pv[1]) + fabsf(pv[2]) + fabsf(pv[3]);
        }
      }
    }
  }

#pragma unroll
  for (int off = 1; off < 64; off <<= 1) pd += __shfl_xor(pd, off);
  if (lane == 0) wred[wv] = pd;
  __syncthreads();
  if (tid == 0)
    partials[lid] = wred[0] + wred[1] + wred[2] + wred[3] +
                    wred[4] + wred[5] + wred[6] + wred[7];
}

// ---------------------------------------------------------------------------
__global__ __launch_bounds__(256) void state_update_kernel(
    FState* __restrict__ st, const float* __restrict__ partials, int iter)
{
  const int tid = threadIdx.x;
  float s = partials[tid] + partials[tid + 256];
  __shared__ float red[256];
  red[tid] = s;
  __syncthreads();
  for (int off = 128; off > 0; off >>= 1) {
    if (tid < off) red[tid] += red[tid + off];
    __syncthreads();
  }
  if (tid == 0) {
    const int done_prev = st->done;
    st->done_prev = done_prev;
    if (!done_prev) {
      const float diff = red[0] * (1.0f / (float)NHE);
      const bool conv = (diff < st->thr + st->fac * diff) && (iter > 0);
      st->upd  = conv ? 0 : 1;
      st->done = conv ? 1 : 0;
      if (!conv) {
        const int cw = st->cw;
        const int up = (int)((float)cw * 1.1f);
        const int dn = (int)((float)cw * 0.9f);
        int nw = (diff > 0.05f) ? up : ((diff < 0.001f && cw > 64) ? dn : cw);
        nw = nw < 64 ? 64 : (nw > TDIM ? TDIM : nw);
        st->cw = nw;
        st->temp += 0.005f;
      }
    } else {
      st->upd = 0;
    }
  }
}

// ---------------------------------------------------------------------------
extern "C" void kernel_launch(void* const* d_in, const int* in_sizes, int n_in,
                              void* d_out, int out_size, void* d_ws, size_t ws_size,
                              hipStream_t stream)
{
  const float* x   = (const float*)d_in[0];
  const float* Wq  = (const float*)d_in[1];
  const float* bq  = (const float*)d_in[2];
  const float* Wk  = (const float*)d_in[3];
  const float* Wv  = (const float*)d_in[4];
  const float* bv  = (const float*)d_in[5];
  const float* Wo  = (const float*)d_in[6];
  const float* bo  = (const float*)d_in[7];
  const float* lna = (const float*)d_in[8];
  const float* lnb = (const float*)d_in[9];
  const float* lnc = (const float*)d_in[10];
  const float* lnd = (const float*)d_in[11];
  const float* lqw = (const float*)d_in[12];
  const float* lqb = (const float*)d_in[13];
  const float* lkw = (const float*)d_in[14];
  const float* lkb = (const float*)d_in[15];
  const float* lvw = (const float*)d_in[16];
  const float* lvb = (const float*)d_in[17];
  const float* thr = (const float*)d_in[18];
  const float* tb  = (const float*)d_in[19];
  const float* fac = (const float*)d_in[20];
  float* out = (float*)d_out;

  // workspace layout (~52 MB)
  float* f0   = (float*)d_ws;
  float* qcur = f0;                       // f32 head layout, 8MB (in-place updated)
  float* io0  = f0 + (size_t)NHE;         // f32 (k-heads temp, then iter_out ping)
  float* io1  = f0 + 2 * (size_t)NHE;     // f32 (v-heads temp, then iter_out pong)
  _Float16* h0   = (_Float16*)(f0 + 3 * (size_t)NHE);
  _Float16* xaH  = h0;                         // [2048][1024] fp16 (aliases attnH)
  _Float16* attnH = h0;
  _Float16* xbH  = h0 + (size_t)RROWS * 1024;
  _Float16* WqH  = xbH + (size_t)RROWS * 1024; // [1024][1024] fp16 each
  _Float16* WkH  = WqH + (size_t)1048576;
  _Float16* WvH  = WkH + (size_t)1048576;
  _Float16* WoH  = WvH + (size_t)1048576;
  _Float16* lqwH = WoH + (size_t)1048576;      // [64][64] fp16
  unsigned short* skb = (unsigned short*)(lqwH + 4096);  // bf16 [bh][t][hd]
  unsigned short* vpT = skb + (size_t)NHE;               // bf16 [bh][hd][t]
  float* partials = (float*)(vpT + (size_t)NHE);
  FState* st = (FState*)(partials + DIFF_BLOCKS);

  constexpr float SC = 0.35355339059327379f;  // 64^-0.25

  // prep: init + LN(x) + weight conversion in one launch
  hipLaunchKernelGGL(prep_kernel, dim3(6149), dim3(256), 0, stream,
                     x, lna, lnb, xaH, xbH,
                     Wq, Wk, Wv, Wo, lqw, WqH, WkH, WvH, WoH, lqwH,
                     st, thr, tb, fac);

  // fused QKV fp16 MFMA GEMMs -> f32 head layouts (qcur, io0=k, io1=v)
  hipLaunchKernelGGL((gemm_mfma_kernel<1>), dim3(16, 8, 3), dim3(256), 0, stream,
                     xaH, WqH, bq, qcur, SC,
                     xbH, WkH, (const float*)nullptr, io0, SC,
                     xbH, WvH, bv, io1, 1.0f);

  // iteration-invariant head projections (k -> skb, v -> vpT) in one launch
  hipLaunchKernelGGL(headproj_kv_kernel, dim3(1024, 2), dim3(256), 0, stream,
                     io0, skb, lkw, lkb, lnd, io1, vpT, lvw, lvb);

  for (int it = 0; it < 3; ++it) {
    float* io   = (it & 1) ? io1 : io0;
    float* prev = (it & 1) ? io0 : io1;
    hipLaunchKernelGGL(attn_mfma_kernel, dim3(DIFF_BLOCKS), dim3(512), 0, stream,
                       qcur, skb, vpT, io, prev, attnH, lqwH, lqb, lnc,
                       partials, st, it == 0 ? 1 : 0);
    hipLaunchKernelGGL(state_update_kernel, dim3(1), dim3(256), 0, stream,
                       st, partials, it);
  }

  // final fp16 MFMA GEMM: out = attn @ Wo^T + bo (row-major f32)
  hipLaunchKernelGGL((gemm_mfma_kernel<0>), dim3(16, 8, 1), dim3(256), 0, stream,
                     attnH, WoH, bo, out, 1.0f,
                     attnH, WoH, bo, out, 1.0f,
                     attnH, WoH, bo, out, 1.0f);
}